// Round 7
// baseline (9215.943 us; speedup 1.0000x reference)
//
#include <hip/hip_runtime.h>
#include <math.h>

// ---------------------------------------------------------------------------
// DisableGateLSTM: 512-step LSTM over 64 independent chains.
// R7: phase-machinery teardown. 4 groups x 64 blocks (1/CU), 16 chains/group,
// block j owns units [8j,8j+8) = 32 gate rows; weights LDS-resident (R4 GEMM
// kept verbatim in layout/indexing -- it is numerics-proven).
//  - h exchange: TAGGED 8B atomics (hi=step tag, lo=f32 h). Self-validating
//    data: no flags, no store->flag ordering, no extra round trip.
//  - wave-local pipeline: wave w depends only on producers [8w,8w+8) for its
//    k-window [64w,64w+64); polls+stages+computes independently.
//  - ONE __syncthreads per step (was 5): k-split reduce via LDS atomicAdd
//    into triple-buffered, bias-preinit gate accumulators; c,m in registers.
// R1 lesson: relaxed atomics only (no acquire/release maintenance in loop).
// R2 lesson: exact libm expf/tanhf. R3 lesson: injective LDS maps only.
// R6 lesson: ~7.5us/phase fixed cost -> minimize phases, not payload.
// ---------------------------------------------------------------------------

#define BATCH   64
#define SEQ     512
#define EMBED   256
#define HIDDEN  512
#define GD      768
#define CLASSES 4

#define NBLK    256
#define NTHR    512
#define GROUPS  4
#define GB      64
#define CPG     16
#define UPB     8
#define ROWS    32

#define SWHS 532
#define SWXS 276
#define SHS  544
#define SXS  268
#define SGB  544            // gate buffer: 32 rows * stride 17

typedef unsigned long long ull;

__global__ __launch_bounds__(NTHR, 1) void lstm_persistent(
    const int*   __restrict__ ids,
    const float* __restrict__ emb,
    const float* __restrict__ Wf, const float* __restrict__ bf,
    const float* __restrict__ Wi, const float* __restrict__ bi,
    const float* __restrict__ Wo, const float* __restrict__ bo,
    const float* __restrict__ Wc, const float* __restrict__ bc,
    const float* __restrict__ fcw,
    const float* __restrict__ fcb,
    float* __restrict__ out,
    void*  __restrict__ wsv)
{
  __shared__ __align__(16) float sWh[ROWS * SWHS];   // 68,096 B
  __shared__ __align__(16) float sWx[ROWS * SWXS];   // 35,328 B
  __shared__ __align__(16) float sH [CPG * SHS];     // 34,816 B (+ GEMV scratch)
  __shared__ __align__(16) float sX [CPG * SXS];     // 17,152 B
  __shared__ float sGate[3 * SGB];                   //  6,528 B (triple buffer)
  __shared__ float sB[ROWS];                         //    128 B

  const int tid = threadIdx.x;
  const int bid = blockIdx.x;
  const int g   = bid & 3;        // group: blocks of a group sit on 2 XCDs
  const int j   = bid >> 2;       // in-group rank 0..63
  const int u0  = j * UPB;
  const int chBase = g * CPG;

  ull* hbuf = (ull*)wsv;                          // [2][64][512] tagged h
  ull* wmax = hbuf + (size_t)2 * BATCH * HIDDEN;  // [64][512] tagged max

  // ---- weights -> LDS (R4 layout, skew by gate), once ----
  for (int r = 0; r < ROWS; ++r) {
    const float* W = (r < 8) ? Wf : (r < 16) ? Wi : (r < 24) ? Wo : Wc;
    const float* src = W + (size_t)(u0 + (r & 7)) * GD;
    const int skw = ((r >> 3) & 3) * 4;
    float* dh = sWh + r * SWHS + skw;
    float* dxw = sWx + r * SWXS + skw;
    for (int col = tid; col < GD; col += NTHR) {
      float v = src[col];
      if (col < HIDDEN) dh[col] = v;
      else              dxw[col - HIDDEN] = v;
    }
  }
  if (tid < ROWS) {
    const float* bv = (tid < 8) ? bf : (tid < 16) ? bi : (tid < 24) ? bo : bc;
    sB[tid] = bv[u0 + (tid & 7)];
  }
  __syncthreads();
  // preinit gate buffer 0 with biases (buffers 1,2 are inited in-loop)
  sGate[0 * SGB + (tid >> 4) * 17 + (tid & 15)] = sB[tid >> 4];
  __syncthreads();

  // GEMM tiling (R4): frag 4 rows x 4 chains; k split 16 ways.
  const int cg = tid & 3;
  const int rg = (tid >> 2) & 7;
  const int ks = tid >> 5;
  const int w  = tid >> 6;         // wave 0..7: owns k [64w,64w+64), e [32w,+32)

  const int lch = tid & 15;        // staging: chain
  const int seg = (tid >> 4) & 3;  // staging: segment within wave chunk

  const float* pH0  = sH  + (cg * 4) * SHS  + cg * 4 + ks * 32;
  const float* pX0  = sX  + (cg * 4) * SXS  + cg * 4 + ks * 16;
  const float* pW0  = sWh + (rg * 4) * SWHS + ((rg >> 1) & 3) * 4 + ks * 32;
  const float* pWx0 = sWx + (rg * 4) * SWXS + ((rg >> 1) & 3) * 4 + ks * 16;

  float* dx = sX + lch * SXS + (lch >> 2) * 4 + w * 32 + seg * 8;
  float* dh = sH + lch * SHS + (lch >> 2) * 4 + w * 64 + seg * 16;
  const int idOfs = (chBase + lch) * SEQ;
  const int xOfs  = w * 32 + seg * 8;

  const int guu = tid >> 4, gch = tid & 15;   // gate-lane role (tid<128)
  float cReg = 0.0f, mReg = -3.402823e38f;

  for (int t = 0; t < SEQ; ++t) {
    const int pb  = t & 1;
    const int b3  = t % 3;
    const int b3n = (t + 1) % 3;

    float acc[4][4];
    #pragma unroll
    for (int a = 0; a < 4; ++a)
      #pragma unroll
      for (int b2 = 0; b2 < 4; ++b2) acc[a][b2] = 0.0f;

    // ---- x: wave-local load -> sX (no cross-wave sync needed) ----
    {
      int id = ids[idOfs + t];
      const float* xs = emb + (size_t)id * EMBED + xOfs;
      float4 xa = *(const float4*)xs;
      float4 xb = *(const float4*)(xs + 4);
      *(float4*)dx = xa;
      *(float4*)(dx + 4) = xb;
    }
    // ---- x-GEMM (overlaps remote producers finishing h_t) ----
    #pragma unroll
    for (int kk = 0; kk < 4; ++kk) {
      float4 xv[4], wv[4];
      #pragma unroll
      for (int ci = 0; ci < 4; ++ci)
        xv[ci] = *(const float4*)(pX0 + ci * SXS + kk * 4);
      #pragma unroll
      for (int ri = 0; ri < 4; ++ri)
        wv[ri] = *(const float4*)(pWx0 + ri * SWXS + kk * 4);
      #pragma unroll
      for (int ri = 0; ri < 4; ++ri)
        #pragma unroll
        for (int ci = 0; ci < 4; ++ci) {
          acc[ri][ci] = fmaf(wv[ri].x, xv[ci].x, acc[ri][ci]);
          acc[ri][ci] = fmaf(wv[ri].y, xv[ci].y, acc[ri][ci]);
          acc[ri][ci] = fmaf(wv[ri].z, xv[ci].z, acc[ri][ci]);
          acc[ri][ci] = fmaf(wv[ri].w, xv[ci].w, acc[ri][ci]);
        }
    }

    // ---- h: tag-poll + stage (wave-local: only this wave's 8 producers) ----
    {
      const ull* hp = hbuf + ((size_t)pb * BATCH + chBase + lch) * HIDDEN
                           + w * 64 + seg * 16;
      ull v[16];
      bool ok;
      do {
        ok = true;
        #pragma unroll
        for (int i = 0; i < 16; ++i) {
          v[i] = __hip_atomic_load(hp + i, __ATOMIC_RELAXED,
                                   __HIP_MEMORY_SCOPE_AGENT);
          ok = ok && ((unsigned)(v[i] >> 32) >= (unsigned)t);
        }
      } while (!__all(ok));
      #pragma unroll
      for (int q = 0; q < 4; ++q) {
        float4 hq;
        hq.x = __uint_as_float((unsigned)v[q * 4 + 0]);
        hq.y = __uint_as_float((unsigned)v[q * 4 + 1]);
        hq.z = __uint_as_float((unsigned)v[q * 4 + 2]);
        hq.w = __uint_as_float((unsigned)v[q * 4 + 3]);
        *(float4*)(dh + q * 4) = hq;
      }
    }
    // ---- h-GEMM over this thread's k window ----
    #pragma unroll
    for (int kk = 0; kk < 8; ++kk) {
      float4 hv[4], wv[4];
      #pragma unroll
      for (int ci = 0; ci < 4; ++ci)
        hv[ci] = *(const float4*)(pH0 + ci * SHS + kk * 4);
      #pragma unroll
      for (int ri = 0; ri < 4; ++ri)
        wv[ri] = *(const float4*)(pW0 + ri * SWHS + kk * 4);
      #pragma unroll
      for (int ri = 0; ri < 4; ++ri)
        #pragma unroll
        for (int ci = 0; ci < 4; ++ci) {
          acc[ri][ci] = fmaf(wv[ri].x, hv[ci].x, acc[ri][ci]);
          acc[ri][ci] = fmaf(wv[ri].y, hv[ci].y, acc[ri][ci]);
          acc[ri][ci] = fmaf(wv[ri].z, hv[ci].z, acc[ri][ci]);
          acc[ri][ci] = fmaf(wv[ri].w, hv[ci].w, acc[ri][ci]);
        }
    }

    // ---- pair ks-slices in-wave, then LDS atomic reduce into sGate[b3] ----
    #pragma unroll
    for (int ri = 0; ri < 4; ++ri)
      #pragma unroll
      for (int ci = 0; ci < 4; ++ci)
        acc[ri][ci] += __shfl_down(acc[ri][ci], 32);
    if ((tid & 32) == 0) {
      float* gbuf = sGate + b3 * SGB;
      #pragma unroll
      for (int ri = 0; ri < 4; ++ri)
        #pragma unroll
        for (int ci = 0; ci < 4; ++ci)
          atomicAdd(&gbuf[(rg * 4 + ri) * 17 + cg * 4 + ci], acc[ri][ci]);
    }
    // preinit next-next buffer with biases (disjoint from b3 adds & t-1 reads)
    sGate[b3n * SGB + (tid >> 4) * 17 + (tid & 15)] = sB[tid >> 4];

    __syncthreads();   // the ONE block-wide sync per step

    // ---- gates + state + tagged publish (waves 0-1; c,m in registers) ----
    if (tid < 128) {
      const float* gb = sGate + b3 * SGB;
      float pf = gb[( 0 + guu) * 17 + gch];
      float pi = gb[( 8 + guu) * 17 + gch];
      float po = gb[(16 + guu) * 17 + gch];
      float pg = gb[(24 + guu) * 17 + gch];
      float f  = 1.0f / (1.0f + expf(-pf));
      float i_ = 1.0f / (1.0f + expf(-pi));
      float o  = 1.0f / (1.0f + expf(-po));
      float gg = tanhf(pg);
      float cn = f * cReg + i_ * gg;
      float h  = o * tanhf(cn);
      cReg = cn;
      mReg = fmaxf(mReg, h);
      ull pv = ((ull)(unsigned)(t + 1) << 32) | (ull)__float_as_uint(h);
      __hip_atomic_store(
          hbuf + ((size_t)(pb ^ 1) * BATCH + chBase + gch) * HIDDEN + u0 + guu,
          pv, __ATOMIC_RELAXED, __HIP_MEMORY_SCOPE_AGENT);
    }
  }

  // ---- publish tagged running max ----
  if (tid < 128) {
    ull pv = (1ULL << 32) | (ull)__float_as_uint(mReg);
    __hip_atomic_store(wmax + (size_t)(chBase + gch) * HIDDEN + u0 + guu,
                       pv, __ATOMIC_RELAXED, __HIP_MEMORY_SCOPE_AGENT);
  }

  // ---- head GEMV on group-leader blocks (tag-polled; no barrier) ----
  if (j == 0) {
    const int ch = tid & 15, cls = (tid >> 4) & 3, us = tid >> 6;
    const ull* mp = wmax + (size_t)(chBase + ch) * HIDDEN + us * 64;
    const float* wrow = fcw + (size_t)cls * HIDDEN + us * 64;
    float s = 0.0f;
    for (int q0 = 0; q0 < 64; q0 += 8) {
      ull vv[8];
      bool ok;
      do {
        ok = true;
        #pragma unroll
        for (int i = 0; i < 8; ++i) {
          vv[i] = __hip_atomic_load(mp + q0 + i, __ATOMIC_RELAXED,
                                    __HIP_MEMORY_SCOPE_AGENT);
          ok = ok && ((unsigned)(vv[i] >> 32) >= 1u);
        }
      } while (!__all(ok));
      #pragma unroll
      for (int i = 0; i < 8; ++i)
        s = fmaf(__uint_as_float((unsigned)vv[i]), wrow[q0 + i], s);
    }
    sH[tid] = s;                    // scratch: layout == tid
    __syncthreads();
    if (tid < 64) {
      float tot = fcb[(tid >> 4) & 3];
      #pragma unroll
      for (int q = 0; q < 8; ++q) tot += sH[q * 64 + tid];
      out[(chBase + (tid & 15)) * CLASSES + ((tid >> 4) & 3)] = tot;
    }
  }
}

extern "C" void kernel_launch(void* const* d_in, const int* in_sizes, int n_in,
                              void* d_out, int out_size, void* d_ws, size_t ws_size,
                              hipStream_t stream) {
  const int*   ids = (const int*)  d_in[0];
  const float* emb = (const float*)d_in[1];
  const float* Wf  = (const float*)d_in[2];
  const float* bf  = (const float*)d_in[3];
  const float* Wi  = (const float*)d_in[4];
  const float* bi  = (const float*)d_in[5];
  const float* Wo  = (const float*)d_in[6];
  const float* bo  = (const float*)d_in[7];
  const float* Wc  = (const float*)d_in[8];
  const float* bc  = (const float*)d_in[9];
  const float* fcw = (const float*)d_in[10];
  const float* fcb = (const float*)d_in[11];

  // Zero ALL tagged buffers: hbuf [2][64][512] + wmax [64][512] (8B each).
  // Mandatory: 0xAA poison would parse as a huge valid tag.
  hipMemsetAsync(d_ws, 0, (size_t)3 * BATCH * HIDDEN * sizeof(ull), stream);

  lstm_persistent<<<dim3(NBLK), dim3(NTHR), 0, stream>>>(
      ids, emb, Wf, bf, Wi, bi, Wo, bo, Wc, bc, fcw, fcb,
      (float*)d_out, d_ws);
}

// Round 8
// 6142.641 us; speedup vs baseline: 1.5003x; 1.5003x over previous
//
#include <hip/hip_runtime.h>
#include <math.h>

// ---------------------------------------------------------------------------
// DisableGateLSTM R8: 4 groups x 64 blocks (1/CU), group owns 16 chains,
// block j owns units [8j,8j+8) (32 gate rows, weights LDS-resident).
// Lessons baked in: relaxed atomics only (R1); libm gates (R2); injective
// LDS maps (R3); minimize phases (R6); minimize POLLED LLC lines (R7:
// sync cost tracks poll footprint -- single root word per group only).
// New: ONE __syncthreads/step; wave-private sH/sX (stage needs no barrier);
// LDS-atomicAdd gate reduction (triple-buffered, bias-preinit); tree
// arrival (8 leaves + fire-and-forget root; root IS the generation word);
// per-wave s_waitcnt drain + LDS rendezvous instead of a drain barrier;
// x-GEMM pipelined one step ahead, off the critical path.
// ---------------------------------------------------------------------------

#define BATCH   64
#define SEQ     512
#define EMBED   256
#define HIDDEN  512
#define GD      768
#define CLASSES 4

#define NBLK    256
#define NTHR    512
#define GROUPS  4
#define GB      64
#define CPG     16
#define UPB     8
#define ROWS    32

#define SWHS 532
#define SWXS 276
#define SHS  544
#define SXS  268
#define SGS  544            // one gate accum buffer: 32 rows * stride 17

typedef unsigned long long ull;
typedef unsigned long long __attribute__((may_alias)) ull_a;

__global__ __launch_bounds__(NTHR, 1) void lstm_persistent(
    const int*   __restrict__ ids,
    const float* __restrict__ emb,
    const float* __restrict__ Wf, const float* __restrict__ bf,
    const float* __restrict__ Wi, const float* __restrict__ bi,
    const float* __restrict__ Wo, const float* __restrict__ bo,
    const float* __restrict__ Wc, const float* __restrict__ bc,
    const float* __restrict__ fcw,
    const float* __restrict__ fcb,
    float* __restrict__ out,
    float* __restrict__ ws)
{
  __shared__ __align__(16) float sWh[ROWS * SWHS];   // 68,096 B
  __shared__ __align__(16) float sWx[ROWS * SWXS];   // 35,328 B
  __shared__ __align__(16) float sH [CPG * SHS];     // 34,816 B
  __shared__ __align__(16) float sX [CPG * SXS];     // 17,152 B
  __shared__ float gbuf[3 * SGS];                    //  6,528 B
  __shared__ float sB[ROWS];
  __shared__ unsigned sArr;
  __shared__ int sDone;

  const int tid = threadIdx.x;
  const int bid = blockIdx.x;
  const int g   = bid & 3;
  const int j   = bid >> 2;
  const int u0  = j * UPB;
  const int chBase = g * CPG;

  float* hbuf = ws;                                   // [2][64][512]
  float* wmax = ws + (size_t)2 * BATCH * HIDDEN;      // [64][512]
  unsigned* tree = (unsigned*)(ws + (size_t)3 * BATCH * HIDDEN);
  unsigned* leaf = tree + g * 160 + (j >> 3) * 16;    // 8 leaf lines/group
  unsigned* root = tree + g * 160 + 128;              // root = generation word

  // ---- weights -> LDS (R4 skewed layout), once ----
  for (int r = 0; r < ROWS; ++r) {
    const float* W = (r < 8) ? Wf : (r < 16) ? Wi : (r < 24) ? Wo : Wc;
    const float* src = W + (size_t)(u0 + (r & 7)) * GD;
    const int skw = ((r >> 3) & 3) * 4;
    float* dh = sWh + r * SWHS + skw;
    float* dxw = sWx + r * SWXS + skw;
    for (int col = tid; col < GD; col += NTHR) {
      float v = src[col];
      if (col < HIDDEN) dh[col] = v;
      else              dxw[col - HIDDEN] = v;
    }
  }
  if (tid < ROWS) {
    const float* bv = (tid < 8) ? bf : (tid < 16) ? bi : (tid < 24) ? bo : bc;
    sB[tid] = bv[u0 + (tid & 7)];
  }
  if (tid == 0) { sArr = 0; sDone = 0; }
  __syncthreads();

  // roles
  const int lane = tid & 63;
  const int w    = tid >> 6;        // wave 0..7
  const int cg   = lane & 3;        // chain group (4 chains)
  const int rg   = (lane >> 2) & 7; // row group (4 rows)
  const int kh   = lane >> 5;       // k half within wave window
  const int lch  = lane & 15;       // staging chain
  const int seg  = (lane >> 4) & 3; // staging segment

  // wave-private windows: h-k [64w,64w+64), x-k [32w,32w+32)
  const float* pH = sH  + (cg * 4) * SHS  + cg * 4 + 64 * w + 32 * kh;
  const float* pW = sWh + (rg * 4) * SWHS + ((rg >> 1) & 3) * 4 + 64 * w + 32 * kh;
  const float* pX = sX  + (cg * 4) * SXS  + cg * 4 + 32 * w + 16 * kh;
  const float* pWx= sWx + (rg * 4) * SWXS + ((rg >> 1) & 3) * 4 + 32 * w + 16 * kh;
  float* dxp = sX + lch * SXS + (lch >> 2) * 4 + 32 * w + 8 * seg;
  float* dhp = sH + lch * SHS + (lch >> 2) * 4 + 64 * w + 16 * seg;
  const int idRow = (chBase + lch) * SEQ;

  const int guu = tid >> 4, gch = tid & 15;   // gate-lane role (tid<128)
  float cReg = 0.0f, mReg = -3.402823e38f;

  float acc_x[4][4];
  float4 rx0, rx1;

  // ---- prologue: gbuf[0] preinit, stage x(0), prefetch x(1), x-GEMM(0) ----
  gbuf[0 * SGS + (tid >> 4) * 17 + (tid & 15)] = sB[tid >> 4];
  {
    int id0 = ids[idRow];
    const float* xr = emb + (size_t)id0 * EMBED + 32 * w + 8 * seg;
    *(float4*)dxp = *(const float4*)xr;
    *(float4*)(dxp + 4) = *(const float4*)(xr + 4);
    int id1 = ids[idRow + 1];
    const float* xr1 = emb + (size_t)id1 * EMBED + 32 * w + 8 * seg;
    rx0 = *(const float4*)xr1;
    rx1 = *(const float4*)(xr1 + 4);
  }
  #pragma unroll
  for (int a = 0; a < 4; ++a)
    #pragma unroll
    for (int b2 = 0; b2 < 4; ++b2) acc_x[a][b2] = 0.0f;
  #pragma unroll
  for (int kk = 0; kk < 4; ++kk) {
    float4 xv[4], wv[4];
    #pragma unroll
    for (int ci = 0; ci < 4; ++ci) xv[ci] = *(const float4*)(pX + ci * SXS + kk * 4);
    #pragma unroll
    for (int ri = 0; ri < 4; ++ri) wv[ri] = *(const float4*)(pWx + ri * SWXS + kk * 4);
    #pragma unroll
    for (int ri = 0; ri < 4; ++ri)
      #pragma unroll
      for (int ci = 0; ci < 4; ++ci) {
        acc_x[ri][ci] = fmaf(wv[ri].x, xv[ci].x, acc_x[ri][ci]);
        acc_x[ri][ci] = fmaf(wv[ri].y, xv[ci].y, acc_x[ri][ci]);
        acc_x[ri][ci] = fmaf(wv[ri].z, xv[ci].z, acc_x[ri][ci]);
        acc_x[ri][ci] = fmaf(wv[ri].w, xv[ci].w, acc_x[ri][ci]);
      }
  }
  __syncthreads();   // gbuf[0] preinit complete before step-0 atomicAdds

  for (int t = 0; t < SEQ; ++t) {
    const int pb = t & 1;

    // ---- release: tid0 polls root (ONE line/group), LDS flag fans out ----
    if (tid == 0) {
      while (__hip_atomic_load(root, __ATOMIC_RELAXED, __HIP_MEMORY_SCOPE_AGENT)
             < 8u * (unsigned)t)
        __builtin_amdgcn_s_sleep(1);
      __hip_atomic_store(&sDone, t, __ATOMIC_RELAXED, __HIP_MEMORY_SCOPE_WORKGROUP);
    }
    while (__hip_atomic_load(&sDone, __ATOMIC_RELAXED, __HIP_MEMORY_SCOPE_WORKGROUP) < t) {}

    // ---- stage h(t): wave-private k-window, coherent 8B loads ----
    {
      const float* hs = hbuf + ((size_t)pb * BATCH + chBase + lch) * HIDDEN
                             + 64 * w + 16 * seg;
      #pragma unroll
      for (int i = 0; i < 8; ++i) {
        ull v = __hip_atomic_load((const ull_a*)hs + i, __ATOMIC_RELAXED,
                                  __HIP_MEMORY_SCOPE_AGENT);
        *(ull_a*)(dhp + 2 * i) = v;
      }
    }

    // ---- h-GEMM into acc (seeded with pipelined x-GEMM result) ----
    float acc[4][4];
    #pragma unroll
    for (int a = 0; a < 4; ++a)
      #pragma unroll
      for (int b2 = 0; b2 < 4; ++b2) acc[a][b2] = acc_x[a][b2];
    #pragma unroll
    for (int kk = 0; kk < 8; ++kk) {
      float4 hv[4], wv[4];
      #pragma unroll
      for (int ci = 0; ci < 4; ++ci) hv[ci] = *(const float4*)(pH + ci * SHS + kk * 4);
      #pragma unroll
      for (int ri = 0; ri < 4; ++ri) wv[ri] = *(const float4*)(pW + ri * SWHS + kk * 4);
      #pragma unroll
      for (int ri = 0; ri < 4; ++ri)
        #pragma unroll
        for (int ci = 0; ci < 4; ++ci) {
          acc[ri][ci] = fmaf(wv[ri].x, hv[ci].x, acc[ri][ci]);
          acc[ri][ci] = fmaf(wv[ri].y, hv[ci].y, acc[ri][ci]);
          acc[ri][ci] = fmaf(wv[ri].z, hv[ci].z, acc[ri][ci]);
          acc[ri][ci] = fmaf(wv[ri].w, hv[ci].w, acc[ri][ci]);
        }
    }

    // ---- pair kh halves, reduce via LDS atomicAdd into gbuf[t%3] ----
    #pragma unroll
    for (int ri = 0; ri < 4; ++ri)
      #pragma unroll
      for (int ci = 0; ci < 4; ++ci)
        acc[ri][ci] += __shfl_down(acc[ri][ci], 32);
    if (kh == 0) {
      float* gb = gbuf + (t % 3) * SGS;
      #pragma unroll
      for (int ri = 0; ri < 4; ++ri)
        #pragma unroll
        for (int ci = 0; ci < 4; ++ci)
          atomicAdd(&gb[(rg * 4 + ri) * 17 + cg * 4 + ci], acc[ri][ci]);
    }
    // preinit next-next buffer with biases
    gbuf[((t + 1) % 3) * SGS + (tid >> 4) * 17 + (tid & 15)] = sB[tid >> 4];

    __syncthreads();   // the ONE barrier per step

    // ---- gates + publish + arrival (waves 0-1) ----
    if (tid < 128) {
      const float* gb = gbuf + (t % 3) * SGS;
      float pf = gb[( 0 + guu) * 17 + gch];
      float pi = gb[( 8 + guu) * 17 + gch];
      float po = gb[(16 + guu) * 17 + gch];
      float pg = gb[(24 + guu) * 17 + gch];
      float f  = 1.0f / (1.0f + expf(-pf));
      float i_ = 1.0f / (1.0f + expf(-pi));
      float o  = 1.0f / (1.0f + expf(-po));
      float gg = tanhf(pg);
      float cn = f * cReg + i_ * gg;
      float h  = o * tanhf(cn);
      cReg = cn;
      mReg = fmaxf(mReg, h);
      __hip_atomic_store(
          hbuf + ((size_t)(pb ^ 1) * BATCH + chBase + gch) * HIDDEN + u0 + guu,
          h, __ATOMIC_RELAXED, __HIP_MEMORY_SCOPE_AGENT);
      if ((tid & 63) == 0) {
        __builtin_amdgcn_s_waitcnt(0);              // drain this wave's stores
        unsigned o2 = atomicAdd(&sArr, 1u);         // LDS rendezvous of 2 waves
        if (o2 & 1) {                               // second gate wave: arrive
          unsigned lo = __hip_atomic_fetch_add(leaf, 1u, __ATOMIC_RELAXED,
                                               __HIP_MEMORY_SCOPE_AGENT);
          if (lo == 8u * (unsigned)(t + 1) - 1u)
            __hip_atomic_fetch_add(root, 1u, __ATOMIC_RELAXED,
                                   __HIP_MEMORY_SCOPE_AGENT);  // fire & forget
        }
      }
    }

    // ---- pipelined x path for t+1 (off critical path) ----
    {
      *(float4*)dxp = rx0;
      *(float4*)(dxp + 4) = rx1;
      const int tn = (t + 2 < SEQ) ? t + 2 : SEQ - 1;
      int idn = ids[idRow + tn];
      const float* xr = emb + (size_t)idn * EMBED + 32 * w + 8 * seg;
      rx0 = *(const float4*)xr;
      rx1 = *(const float4*)(xr + 4);
    }
    #pragma unroll
    for (int a = 0; a < 4; ++a)
      #pragma unroll
      for (int b2 = 0; b2 < 4; ++b2) acc_x[a][b2] = 0.0f;
    #pragma unroll
    for (int kk = 0; kk < 4; ++kk) {
      float4 xv[4], wv[4];
      #pragma unroll
      for (int ci = 0; ci < 4; ++ci) xv[ci] = *(const float4*)(pX + ci * SXS + kk * 4);
      #pragma unroll
      for (int ri = 0; ri < 4; ++ri) wv[ri] = *(const float4*)(pWx + ri * SWXS + kk * 4);
      #pragma unroll
      for (int ri = 0; ri < 4; ++ri)
        #pragma unroll
        for (int ci = 0; ci < 4; ++ci) {
          acc_x[ri][ci] = fmaf(wv[ri].x, xv[ci].x, acc_x[ri][ci]);
          acc_x[ri][ci] = fmaf(wv[ri].y, xv[ci].y, acc_x[ri][ci]);
          acc_x[ri][ci] = fmaf(wv[ri].z, xv[ci].z, acc_x[ri][ci]);
          acc_x[ri][ci] = fmaf(wv[ri].w, xv[ci].w, acc_x[ri][ci]);
        }
    }
  }

  // ---- publish running max + final arrival (pseudo-step SEQ) ----
  if (tid < 128) {
    __hip_atomic_store(wmax + (size_t)(chBase + gch) * HIDDEN + u0 + guu,
                       mReg, __ATOMIC_RELAXED, __HIP_MEMORY_SCOPE_AGENT);
    if ((tid & 63) == 0) {
      __builtin_amdgcn_s_waitcnt(0);
      unsigned o2 = atomicAdd(&sArr, 1u);
      if (o2 & 1) {
        unsigned lo = __hip_atomic_fetch_add(leaf, 1u, __ATOMIC_RELAXED,
                                             __HIP_MEMORY_SCOPE_AGENT);
        if (lo == 8u * (unsigned)(SEQ + 1) - 1u)
          __hip_atomic_fetch_add(root, 1u, __ATOMIC_RELAXED,
                                 __HIP_MEMORY_SCOPE_AGENT);
      }
    }
  }

  // ---- head GEMV on group-leader blocks ----
  if (j == 0) {
    if (tid == 0) {
      while (__hip_atomic_load(root, __ATOMIC_RELAXED, __HIP_MEMORY_SCOPE_AGENT)
             < 8u * (unsigned)(SEQ + 1))
        __builtin_amdgcn_s_sleep(1);
    }
    __syncthreads();

    const int ch = tid & 15, cls = (tid >> 4) & 3, us = tid >> 6;
    const float* mrow = wmax + (size_t)(chBase + ch) * HIDDEN + us * 64;
    const float* wrow = fcw + (size_t)cls * HIDDEN + us * 64;
    float s = 0.0f;
    for (int q = 0; q < 64; ++q) {
      float v = __hip_atomic_load(mrow + q, __ATOMIC_RELAXED,
                                  __HIP_MEMORY_SCOPE_AGENT);
      s = fmaf(v, wrow[q], s);
    }
    sH[tid] = s;
    __syncthreads();
    if (tid < 64) {
      float tot = fcb[(tid >> 4) & 3];
      #pragma unroll
      for (int q = 0; q < 8; ++q) tot += sH[q * 64 + tid];
      out[(chBase + (tid & 15)) * CLASSES + ((tid >> 4) & 3)] = tot;
    }
  }
}

extern "C" void kernel_launch(void* const* d_in, const int* in_sizes, int n_in,
                              void* d_out, int out_size, void* d_ws, size_t ws_size,
                              hipStream_t stream) {
  const int*   ids = (const int*)  d_in[0];
  const float* emb = (const float*)d_in[1];
  const float* Wf  = (const float*)d_in[2];
  const float* bf  = (const float*)d_in[3];
  const float* Wi  = (const float*)d_in[4];
  const float* bi  = (const float*)d_in[5];
  const float* Wo  = (const float*)d_in[6];
  const float* bo  = (const float*)d_in[7];
  const float* Wc  = (const float*)d_in[8];
  const float* bc  = (const float*)d_in[9];
  const float* fcw = (const float*)d_in[10];
  const float* fcb = (const float*)d_in[11];

  // zero h0 (hbuf buffer 0) and the arrival tree (monotone counters)
  hipMemsetAsync(d_ws, 0, (size_t)BATCH * HIDDEN * sizeof(float), stream);
  hipMemsetAsync((char*)d_ws + (size_t)3 * BATCH * HIDDEN * sizeof(float),
                 0, 4096, stream);

  lstm_persistent<<<dim3(NBLK), dim3(NTHR), 0, stream>>>(
      ids, emb, Wf, bf, Wi, bi, Wo, bo, Wc, bc, fcw, fcb,
      (float*)d_out, (float*)d_ws);
}